// Round 10
// baseline (177.612 us; speedup 1.0000x reference)
//
#include <hip/hip_runtime.h>

#define B_N 32768
#define D 512
#define DD (D * D)
#define NLEV 10
#define TM 128
#define TN 256
#define BK 32
#define NITER (D / BK)            // 16
#define NHB 128                   // histogram blocks (B_N / 256)
#define MROWS_MAX 34048           // 32768 + 10*128 padding headroom
#define MAX_RT (MROWS_MAX / TM)   // 266

typedef unsigned short u16;
typedef short s16x8 __attribute__((ext_vector_type(8)));
typedef u16 u16x8 __attribute__((ext_vector_type(8)));
typedef float f32x4 __attribute__((ext_vector_type(4)));

__device__ __forceinline__ u16 f2bf(float f) {
  union { float f; unsigned u; } v; v.f = f;
  unsigned r = v.u + 0x7fffu + ((v.u >> 16) & 1u);  // RNE
  return (u16)(r >> 16);
}
__device__ __forceinline__ int clampv(int v) {
  return v < 0 ? 0 : (v > NLEV - 1 ? NLEV - 1 : v);
}

// ---- K1: weff-build (blocks 0..1023) UNION hist+perm-fill (blocks 1024..1151)
__global__ void k1(const float* __restrict__ W, const float* __restrict__ lg,
                   const float* __restrict__ attn, const int* __restrict__ val,
                   u16* __restrict__ weff, u16* __restrict__ hist,
                   int* __restrict__ perm) {
  const int t = threadIdx.x;
  if (blockIdx.x < DD / 256) {
    __shared__ float c[NLEV * NLEV];
    if (t < NLEV) {
      float g[NLEV], a[NLEV], mx = -1e30f;
      #pragma unroll
      for (int l = 0; l < NLEV; ++l) {
        g[l] = 1.0f / (1.0f + expf(-lg[l]));
        a[l] = attn[t * NLEV + l];
        mx = fmaxf(mx, a[l]);
      }
      float s = 0.f;
      #pragma unroll
      for (int l = 0; l < NLEV; ++l) { a[l] = expf(a[l] - mx); s += a[l]; }
      float inv = 1.0f / s;
      #pragma unroll
      for (int l = 0; l < NLEV; ++l) {
        float cc = 0.3f * a[l] * inv * g[l];
        if (l == t) cc += 0.7f * g[t];
        c[t * NLEV + l] = cc;
      }
    }
    __syncthreads();
    const int idx = blockIdx.x * 256 + t;
    float w[NLEV];
    #pragma unroll
    for (int l = 0; l < NLEV; ++l) w[l] = W[l * DD + idx];
    #pragma unroll
    for (int v = 0; v < NLEV; ++v) {
      float s = 0.f;
      #pragma unroll
      for (int l = 0; l < NLEV; ++l) s += c[v * NLEV + l] * w[l];
      weff[v * DD + idx] = f2bf(s);
    }
  } else {
    __shared__ int lc[NLEV];
    const int b = blockIdx.x - DD / 256;   // 0..127
    if (t < NLEV) lc[t] = 0;
    __syncthreads();
    const int gid = b * 256 + t;
    atomicAdd(&lc[clampv(val[gid])], 1);
    perm[gid] = -1;
    if (b < (MROWS_MAX - B_N) / 256) perm[B_N + b * 256 + t] = -1;
    __syncthreads();
    if (t < NLEV) hist[b * NLEV + t] = (u16)lc[t];
  }
}

// ---- K2: deterministic counting-sort scatter (prefix over hist table) ------
__global__ void k2(const int* __restrict__ val, const u16* __restrict__ hist,
                   int* __restrict__ perm, int* __restrict__ starts) {
  __shared__ int h[NHB * NLEV];
  __shared__ int st[NLEV + 1];
  __shared__ int cnt[NLEV];
  __shared__ int lc[NLEV];
  const int t = threadIdx.x, b = blockIdx.x;
  for (int i = t; i < NHB * NLEV; i += 256) h[i] = hist[i];
  if (t < NLEV) lc[t] = 0;
  __syncthreads();
  if (t < NLEV) {
    int run = 0;
    for (int bb = 0; bb < NHB; ++bb) {
      int x = h[bb * NLEV + t];
      h[bb * NLEV + t] = run;
      run += x;
    }
    cnt[t] = run;
  }
  __syncthreads();
  if (t == 0) {
    int s = 0;
    for (int v = 0; v < NLEV; ++v) {
      st[v] = s;
      s += (cnt[v] + TM - 1) & ~(TM - 1);
    }
    st[NLEV] = s;
  }
  __syncthreads();
  const int gid = b * 256 + t;
  const int v = clampv(val[gid]);
  const int pos = atomicAdd(&lc[v], 1);
  perm[st[v] + h[b * NLEV + v] + pos] = gid;
  if (b == 0 && t <= NLEV) starts[t] = st[t];
}

// ---- K3: grouped GEMM, 128x256, all-gload_lds, f32-A + in-reg cvt_pk -------
// R9's verified zero-register-consume loop, minus the xa pre-conversion:
//  * A staged as f32 straight from x via global_load_lds (16B chunks,
//    source pre-swizzled with 16B-granule XOR keyed on row&7; LDS linear).
//  * A frags read as 2x ds_read_b128 f32, converted in-register with
//    v_cvt_pk_bf16_f32 (16 instr/lane/iter) -- no vmem register consume.
//  * double-double buffers (64KB -> 2 blocks/CU); staging issued at TOP of
//    body, waited at END (full ~3k-cy body of slack vs ~900cy HBM).
__global__ __launch_bounds__(512, 4) void k3(
    const float* __restrict__ x, const u16* __restrict__ weff,
    const int* __restrict__ perm, const int* __restrict__ starts,
    const float* __restrict__ bias, float* __restrict__ out) {
  __shared__ float Asf[2][TM * BK];  // 2 x 16 KB (f32 A tile)
  __shared__ u16   Bsu[2][TN * BK];  // 2 x 16 KB (bf16 B tile)

  const int ct = blockIdx.x, rt = blockIdx.y;
  const int Mpad = starts[NLEV];
  if (rt * TM >= Mpad) return;

  int v = 0;
  #pragma unroll
  for (int i = 1; i < NLEV; ++i) if (rt * TM >= starts[i]) v = i;

  const int tid = threadIdx.x;
  const int lane = tid & 63, wave = tid >> 6;
  const int wm = (wave >> 2) * 64, wn = (wave & 3) * 64;
  const int fm = lane & 15;
  const int cb = lane >> 4;

  // ---- A staging (f32): 1024 16B-chunks; chunk c -> row c>>3, slot c&7.
  // Slot s of row r holds logical k-chunk (s ^ (r&7)) via SOURCE swizzle.
  // issue0: c = tid (rows 0..63); issue1: c = 512+tid (rows 64..127).
  const int arow = tid >> 3;          // row within half (0..63)
  const int kch = (tid & 7) ^ (arow & 7);   // same key for both halves
  int pr0 = perm[rt * TM + arow];
  int pr1 = perm[rt * TM + 64 + arow];
  if (pr0 < 0) pr0 = 0;
  if (pr1 < 0) pr1 = 0;
  const float* ga0 = x + (size_t)pr0 * D + kch * 4;
  const float* ga1 = x + (size_t)pr1 * D + kch * 4;
  const int adst0 = tid * 4;          // float index (16B chunks, linear)
  const int adst1 = (512 + tid) * 4;

  const u16* wb = weff + ((size_t)v * D + ct * TN) * D;
  // ---- B staging (verified R4/R9): 2 chunks/thread, source pre-swizzled
  const int c0i = wave * 64 + lane;
  const int c1i = 512 + c0i;
  const int n0 = c0i >> 2, s0 = c0i & 3, kc0 = s0 ^ ((n0 >> 1) & 3);
  const int n1 = c1i >> 2, s1 = c1i & 3, kc1 = s1 ^ ((n1 >> 1) & 3);
  const u16* gb0 = wb + n0 * D + kc0 * 8;
  const u16* gb1 = wb + n1 * D + kc1 * 8;
  const int bdst0 = c0i * 8, bdst1 = c1i * 8;

  // A-read slot indices (uniform per lane across frags)
  const int sl0 = (2 * cb) ^ (fm & 7);
  const int sl1 = (2 * cb + 1) ^ (fm & 7);

  f32x4 acc[4][4];
  #pragma unroll
  for (int i = 0; i < 4; ++i)
    #pragma unroll
    for (int j = 0; j < 4; ++j) acc[i][j] = (f32x4){0.f, 0.f, 0.f, 0.f};

  // ---- prologue: stage step 0 into buffers[0]; full drain; barrier ----
  __builtin_amdgcn_global_load_lds(
      (const __attribute__((address_space(1))) void*)ga0,
      (__attribute__((address_space(3))) void*)(Asf[0] + adst0), 16, 0, 0);
  __builtin_amdgcn_global_load_lds(
      (const __attribute__((address_space(1))) void*)ga1,
      (__attribute__((address_space(3))) void*)(Asf[0] + adst1), 16, 0, 0);
  __builtin_amdgcn_global_load_lds(
      (const __attribute__((address_space(1))) void*)gb0,
      (__attribute__((address_space(3))) void*)(Bsu[0] + bdst0), 16, 0, 0);
  __builtin_amdgcn_global_load_lds(
      (const __attribute__((address_space(1))) void*)gb1,
      (__attribute__((address_space(3))) void*)(Bsu[0] + bdst1), 16, 0, 0);
  asm volatile("s_waitcnt vmcnt(0)" ::: "memory");
  __builtin_amdgcn_s_barrier();
  __builtin_amdgcn_sched_barrier(0);

  int p = 0;
  for (int i = 0; i < NITER; ++i) {
    const bool hn = (i + 1 < NITER);
    // (1) issue step-(i+1) staging into buffers[p^1] (4 gload_lds)
    if (hn) {
      const int ko = (i + 1) * BK;
      __builtin_amdgcn_global_load_lds(
          (const __attribute__((address_space(1))) void*)(ga0 + ko),
          (__attribute__((address_space(3))) void*)(Asf[p ^ 1] + adst0), 16, 0, 0);
      __builtin_amdgcn_global_load_lds(
          (const __attribute__((address_space(1))) void*)(ga1 + ko),
          (__attribute__((address_space(3))) void*)(Asf[p ^ 1] + adst1), 16, 0, 0);
      __builtin_amdgcn_global_load_lds(
          (const __attribute__((address_space(1))) void*)(gb0 + ko),
          (__attribute__((address_space(3))) void*)(Bsu[p ^ 1] + bdst0), 16, 0, 0);
      __builtin_amdgcn_global_load_lds(
          (const __attribute__((address_space(1))) void*)(gb1 + ko),
          (__attribute__((address_space(3))) void*)(Bsu[p ^ 1] + bdst1), 16, 0, 0);
    }
    // (2) frags: A = 2x b128 f32 + cvt_pk -> bf16; B = 1x b128 bf16
    const float* Af = (const float*)Asf[p];
    s16x8 af[4], bf[4];
    #pragma unroll
    for (int t4 = 0; t4 < 4; ++t4) {
      const int m = wm + t4 * 16 + fm;
      const f32x4 lo = *(const f32x4*)(Af + m * 32 + sl0 * 4);
      const f32x4 hi = *(const f32x4*)(Af + m * 32 + sl1 * 4);
      union { unsigned w[4]; s16x8 v; } u;
      asm("v_cvt_pk_bf16_f32 %0, %1, %2" : "=v"(u.w[0]) : "v"(lo[0]), "v"(lo[1]));
      asm("v_cvt_pk_bf16_f32 %0, %1, %2" : "=v"(u.w[1]) : "v"(lo[2]), "v"(lo[3]));
      asm("v_cvt_pk_bf16_f32 %0, %1, %2" : "=v"(u.w[2]) : "v"(hi[0]), "v"(hi[1]));
      asm("v_cvt_pk_bf16_f32 %0, %1, %2" : "=v"(u.w[3]) : "v"(hi[2]), "v"(hi[3]));
      af[t4] = u.v;
      const int n = wn + t4 * 16 + fm;
      bf[t4] = *(const s16x8*)(Bsu[p] + n * BK + ((cb ^ ((n >> 1) & 3)) << 3));
    }
    __builtin_amdgcn_s_setprio(1);
    #pragma unroll
    for (int tm = 0; tm < 4; ++tm)
      #pragma unroll
      for (int tn = 0; tn < 4; ++tn)
        acc[tm][tn] = __builtin_amdgcn_mfma_f32_16x16x32_bf16(af[tm], bf[tn], acc[tm][tn], 0, 0, 0);
    __builtin_amdgcn_s_setprio(0);
    if (hn) {
      // (3) end-of-body wait: step-(i+1) staging landed (full body of slack);
      // lgkmcnt(0): my frag reads of buf p returned (buf p rewritten next body)
      asm volatile("s_waitcnt vmcnt(0)" ::: "memory");
      asm volatile("s_waitcnt lgkmcnt(0)" ::: "memory");
      __builtin_amdgcn_s_barrier();
      __builtin_amdgcn_sched_barrier(0);
    }
    p ^= 1;
  }

  // Epilogue: C frag col=lane&15, row=(lane>>4)*4+reg; scatter rows via perm
  float bv[4];
  #pragma unroll
  for (int tn = 0; tn < 4; ++tn) bv[tn] = bias[ct * TN + wn + tn * 16 + fm];
  #pragma unroll
  for (int tm = 0; tm < 4; ++tm) {
    #pragma unroll
    for (int r = 0; r < 4; ++r) {
      const int mrow = wm + tm * 16 + (lane >> 4) * 4 + r;
      const int p2 = perm[rt * TM + mrow];
      if (p2 >= 0) {
        float* o = out + (size_t)p2 * D + ct * TN + wn + fm;
        #pragma unroll
        for (int tn = 0; tn < 4; ++tn)
          o[tn * 16] = acc[tm][tn][r] + bv[tn];
      }
    }
  }
}

extern "C" void kernel_launch(void* const* d_in, const int* in_sizes, int n_in,
                              void* d_out, int out_size, void* d_ws, size_t ws_size,
                              hipStream_t stream) {
  const float* x    = (const float*)d_in[0];
  const int*   val  = (const int*)d_in[1];
  const float* W    = (const float*)d_in[2];
  const float* lg   = (const float*)d_in[3];
  const float* attn = (const float*)d_in[4];
  const float* bias = (const float*)d_in[5];
  float* out = (float*)d_out;

  char* ws = (char*)d_ws;
  int* starts = (int*)(ws + 0);          // 11 ints
  u16* hist   = (u16*)(ws + 64);         // 128*10 u16
  int* perm   = (int*)(ws + 2688);       // 34048 ints -> ends 138880
  u16* weff   = (u16*)(ws + 139264);     // 10*512*512 bf16 = 5.24 MB

  k1<<<DD / 256 + NHB, 256, 0, stream>>>(W, lg, attn, val, weff, hist, perm);
  k2<<<NHB, 256, 0, stream>>>(val, hist, perm, starts);
  k3<<<dim3(D / TN, MAX_RT), 512, 0, stream>>>(x, weff, perm, starts, bias, out);
}

// Round 12
// 173.327 us; speedup vs baseline: 1.0247x; 1.0247x over previous
//
#include <hip/hip_runtime.h>

#define B_N 32768
#define D 512
#define DD (D * D)
#define NLEV 10
#define TM 128
#define TN 256
#define BK 32
#define NITER (D / BK)            // 16
#define NHB 128                   // histogram blocks (B_N / 256)
#define MROWS_MAX 34048           // 32768 + 10*128 padding headroom
#define MAX_RT (MROWS_MAX / TM)   // 266

typedef unsigned short u16;
typedef short s16x8 __attribute__((ext_vector_type(8)));
typedef u16 u16x8 __attribute__((ext_vector_type(8)));
typedef float f32x4 __attribute__((ext_vector_type(4)));
typedef unsigned u32x2 __attribute__((ext_vector_type(2)));

__device__ __forceinline__ u16 f2bf(float f) {
  union { float f; unsigned u; } v; v.f = f;
  unsigned r = v.u + 0x7fffu + ((v.u >> 16) & 1u);  // RNE
  return (u16)(r >> 16);
}
__device__ __forceinline__ int clampv(int v) {
  return v < 0 ? 0 : (v > NLEV - 1 ? NLEV - 1 : v);
}

// ---- K1: weff-build (blocks 0..1023) UNION hist+perm-fill (blocks 1024..1151)
__global__ void k1(const float* __restrict__ W, const float* __restrict__ lg,
                   const float* __restrict__ attn, const int* __restrict__ val,
                   u16* __restrict__ weff, u16* __restrict__ hist,
                   int* __restrict__ perm) {
  const int t = threadIdx.x;
  if (blockIdx.x < DD / 256) {
    __shared__ float c[NLEV * NLEV];
    if (t < NLEV) {
      float g[NLEV], a[NLEV], mx = -1e30f;
      #pragma unroll
      for (int l = 0; l < NLEV; ++l) {
        g[l] = 1.0f / (1.0f + expf(-lg[l]));
        a[l] = attn[t * NLEV + l];
        mx = fmaxf(mx, a[l]);
      }
      float s = 0.f;
      #pragma unroll
      for (int l = 0; l < NLEV; ++l) { a[l] = expf(a[l] - mx); s += a[l]; }
      float inv = 1.0f / s;
      #pragma unroll
      for (int l = 0; l < NLEV; ++l) {
        float cc = 0.3f * a[l] * inv * g[l];
        if (l == t) cc += 0.7f * g[t];
        c[t * NLEV + l] = cc;
      }
    }
    __syncthreads();
    const int idx = blockIdx.x * 256 + t;
    float w[NLEV];
    #pragma unroll
    for (int l = 0; l < NLEV; ++l) w[l] = W[l * DD + idx];
    #pragma unroll
    for (int v = 0; v < NLEV; ++v) {
      float s = 0.f;
      #pragma unroll
      for (int l = 0; l < NLEV; ++l) s += c[v * NLEV + l] * w[l];
      weff[v * DD + idx] = f2bf(s);
    }
  } else {
    __shared__ int lc[NLEV];
    const int b = blockIdx.x - DD / 256;   // 0..127
    if (t < NLEV) lc[t] = 0;
    __syncthreads();
    const int gid = b * 256 + t;
    atomicAdd(&lc[clampv(val[gid])], 1);
    perm[gid] = -1;
    if (b < (MROWS_MAX - B_N) / 256) perm[B_N + b * 256 + t] = -1;
    __syncthreads();
    if (t < NLEV) hist[b * NLEV + t] = (u16)lc[t];
  }
}

// ---- K2: deterministic counting-sort scatter (prefix over hist table) ------
__global__ void k2(const int* __restrict__ val, const u16* __restrict__ hist,
                   int* __restrict__ perm, int* __restrict__ starts) {
  __shared__ int h[NHB * NLEV];
  __shared__ int st[NLEV + 1];
  __shared__ int cnt[NLEV];
  __shared__ int lc[NLEV];
  const int t = threadIdx.x, b = blockIdx.x;
  for (int i = t; i < NHB * NLEV; i += 256) h[i] = hist[i];
  if (t < NLEV) lc[t] = 0;
  __syncthreads();
  if (t < NLEV) {
    int run = 0;
    for (int bb = 0; bb < NHB; ++bb) {
      int x = h[bb * NLEV + t];
      h[bb * NLEV + t] = run;
      run += x;
    }
    cnt[t] = run;
  }
  __syncthreads();
  if (t == 0) {
    int s = 0;
    for (int v = 0; v < NLEV; ++v) {
      st[v] = s;
      s += (cnt[v] + TM - 1) & ~(TM - 1);
    }
    st[NLEV] = s;
  }
  __syncthreads();
  const int gid = b * 256 + t;
  const int v = clampv(val[gid]);
  const int pos = atomicAdd(&lc[v], 1);
  perm[st[v] + h[b * NLEV + v] + pos] = gid;
  if (b == 0 && t <= NLEV) starts[t] = st[t];
}

// ---- K3: grouped GEMM, 128x256, all-gload_lds + in-kernel LDS-roundtrip cvt
// (resubmission of R11 after infra failure; audit found no correctness/hang
// path -- barriers uniform, per-lane own-chunk readback, verified layouts)
//  * x f32 gload_lds'd into raw linear staging Xs (issued at TOP of body).
//  * post-MFMA (T14): vmcnt(0); each thread ds_reads back its OWN two 16B
//    chunks (lane-linear b128 = canonical conflict-free), 4x v_cvt_pk_bf16,
//    2x ds_write_b64 into the R4-VERIFIED 64B-row XOR bf16 A layout.
//  * frag reads use only verified-0-conflict patterns (R10's f32 read killed).
//  * LDS 80KB (2 blocks/CU); 1 barrier/iter; ~full-body slack on all loads.
__global__ __launch_bounds__(512, 4) void k3(
    const float* __restrict__ x, const u16* __restrict__ weff,
    const int* __restrict__ perm, const int* __restrict__ starts,
    const float* __restrict__ bias, float* __restrict__ out) {
  __shared__ float Xs[2][TM * BK];   // 2 x 16 KB raw f32 staging
  __shared__ u16   Abf[2][TM * BK];  // 2 x 8 KB  bf16 A tile (R4 layout)
  __shared__ u16   Bsu[2][TN * BK];  // 2 x 16 KB bf16 B tile (R4 layout)

  const int ct = blockIdx.x, rt = blockIdx.y;
  const int Mpad = starts[NLEV];
  if (rt * TM >= Mpad) return;

  int v = 0;
  #pragma unroll
  for (int i = 1; i < NLEV; ++i) if (rt * TM >= starts[i]) v = i;

  const int tid = threadIdx.x;
  const int lane = tid & 63, wave = tid >> 6;
  const int wm = (wave >> 2) * 64, wn = (wave & 3) * 64;
  const int fm = lane & 15;
  const int cb = lane >> 4;

  // ---- A staging: 1024 16B chunks, chunk c -> row c>>3, quad c&7 (linear).
  // thread t owns chunks t (rows 0..63) and 512+t (rows 64..127).
  const int arow = tid >> 3;        // 0..63
  const int aq   = tid & 7;         // 16B quad within row (4 floats)
  int pr0 = perm[rt * TM + arow];
  int pr1 = perm[rt * TM + 64 + arow];
  if (pr0 < 0) pr0 = 0;
  if (pr1 < 0) pr1 = 0;
  const float* ga0 = x + (size_t)pr0 * D + aq * 4;
  const float* ga1 = x + (size_t)pr1 * D + aq * 4;
  const int ad0 = tid * 4;          // float offset of chunk t
  const int ad1 = (512 + tid) * 4;  // float offset of chunk 512+t

  // convert-destination offsets in the bf16 A tile (R4 layout:
  // row r, 16B-slot s holds k-chunk s ^ ((r>>1)&3)); chunk quad aq = half
  // (aq&1) of k-chunk aq>>1. Note ((arow+64)>>1)&3 == (arow>>1)&3.
  const int csl = (aq >> 1) ^ ((arow >> 1) & 3);
  const int co0 = arow * 32 + csl * 8 + (aq & 1) * 4;        // u16 units
  const int co1 = (64 + arow) * 32 + csl * 8 + (aq & 1) * 4;

  const u16* wb = weff + ((size_t)v * D + ct * TN) * D;
  // ---- B staging (verified): 2 chunks/thread, source pre-swizzled
  const int c0i = wave * 64 + lane;
  const int c1i = 512 + c0i;
  const int n0 = c0i >> 2, s0 = c0i & 3, kc0 = s0 ^ ((n0 >> 1) & 3);
  const int n1 = c1i >> 2, s1 = c1i & 3, kc1 = s1 ^ ((n1 >> 1) & 3);
  const u16* gb0 = wb + n0 * D + kc0 * 8;
  const u16* gb1 = wb + n1 * D + kc1 * 8;
  const int bdst0 = c0i * 8, bdst1 = c1i * 8;

  f32x4 acc[4][4];
  #pragma unroll
  for (int i = 0; i < 4; ++i)
    #pragma unroll
    for (int j = 0; j < 4; ++j) acc[i][j] = (f32x4){0.f, 0.f, 0.f, 0.f};

  // ---- prologue: stage B(0), X(0); drain; convert X(0)->Abf[0]; barrier ----
  __builtin_amdgcn_global_load_lds(
      (const __attribute__((address_space(1))) void*)gb0,
      (__attribute__((address_space(3))) void*)(Bsu[0] + bdst0), 16, 0, 0);
  __builtin_amdgcn_global_load_lds(
      (const __attribute__((address_space(1))) void*)gb1,
      (__attribute__((address_space(3))) void*)(Bsu[0] + bdst1), 16, 0, 0);
  __builtin_amdgcn_global_load_lds(
      (const __attribute__((address_space(1))) void*)ga0,
      (__attribute__((address_space(3))) void*)(Xs[0] + ad0), 16, 0, 0);
  __builtin_amdgcn_global_load_lds(
      (const __attribute__((address_space(1))) void*)ga1,
      (__attribute__((address_space(3))) void*)(Xs[0] + ad1), 16, 0, 0);
  asm volatile("s_waitcnt vmcnt(0)" ::: "memory");
  {
    const f32x4 c0 = *(const f32x4*)(Xs[0] + ad0);
    const f32x4 c1 = *(const f32x4*)(Xs[0] + ad1);
    unsigned w0, w1, w2, w3;
    asm("v_cvt_pk_bf16_f32 %0, %1, %2" : "=v"(w0) : "v"(c0[0]), "v"(c0[1]));
    asm("v_cvt_pk_bf16_f32 %0, %1, %2" : "=v"(w1) : "v"(c0[2]), "v"(c0[3]));
    asm("v_cvt_pk_bf16_f32 %0, %1, %2" : "=v"(w2) : "v"(c1[0]), "v"(c1[1]));
    asm("v_cvt_pk_bf16_f32 %0, %1, %2" : "=v"(w3) : "v"(c1[2]), "v"(c1[3]));
    *(u32x2*)(Abf[0] + co0) = (u32x2){w0, w1};
    *(u32x2*)(Abf[0] + co1) = (u32x2){w2, w3};
  }
  asm volatile("s_waitcnt lgkmcnt(0)" ::: "memory");
  __builtin_amdgcn_s_barrier();
  __builtin_amdgcn_sched_barrier(0);

  int p = 0;
  for (int i = 0; i < NITER; ++i) {
    const bool hn = (i + 1 < NITER);
    // (1) issue step-(i+1) staging: B -> Bsu[p^1], X -> Xs[p^1]
    if (hn) {
      const int ko = (i + 1) * BK;
      __builtin_amdgcn_global_load_lds(
          (const __attribute__((address_space(1))) void*)(gb0 + ko),
          (__attribute__((address_space(3))) void*)(Bsu[p ^ 1] + bdst0), 16, 0, 0);
      __builtin_amdgcn_global_load_lds(
          (const __attribute__((address_space(1))) void*)(gb1 + ko),
          (__attribute__((address_space(3))) void*)(Bsu[p ^ 1] + bdst1), 16, 0, 0);
      __builtin_amdgcn_global_load_lds(
          (const __attribute__((address_space(1))) void*)(ga0 + ko),
          (__attribute__((address_space(3))) void*)(Xs[p ^ 1] + ad0), 16, 0, 0);
      __builtin_amdgcn_global_load_lds(
          (const __attribute__((address_space(1))) void*)(ga1 + ko),
          (__attribute__((address_space(3))) void*)(Xs[p ^ 1] + ad1), 16, 0, 0);
    }
    // (2) frag reads: verified-0-conflict bf16 patterns only
    s16x8 af[4], bf[4];
    #pragma unroll
    for (int t4 = 0; t4 < 4; ++t4) {
      const int m = wm + t4 * 16 + fm;
      af[t4] = *(const s16x8*)(Abf[p] + m * BK + ((cb ^ ((m >> 1) & 3)) << 3));
      const int n = wn + t4 * 16 + fm;
      bf[t4] = *(const s16x8*)(Bsu[p] + n * BK + ((cb ^ ((n >> 1) & 3)) << 3));
    }
    // (3) MFMA cluster (covers the staging flight time)
    __builtin_amdgcn_s_setprio(1);
    #pragma unroll
    for (int tm = 0; tm < 4; ++tm)
      #pragma unroll
      for (int tn = 0; tn < 4; ++tn)
        acc[tm][tn] = __builtin_amdgcn_mfma_f32_16x16x32_bf16(af[tm], bf[tn], acc[tm][tn], 0, 0, 0);
    __builtin_amdgcn_s_setprio(0);
    if (hn) {
      // (4) drain this iter's staging; convert X(i+1) -> Abf[p^1]
      //     (own-chunk lane-linear b128 reads; b64 writes, R4 layout)
      asm volatile("s_waitcnt vmcnt(0)" ::: "memory");
      const f32x4 c0 = *(const f32x4*)(Xs[p ^ 1] + ad0);
      const f32x4 c1 = *(const f32x4*)(Xs[p ^ 1] + ad1);
      unsigned w0, w1, w2, w3;
      asm("v_cvt_pk_bf16_f32 %0, %1, %2" : "=v"(w0) : "v"(c0[0]), "v"(c0[1]));
      asm("v_cvt_pk_bf16_f32 %0, %1, %2" : "=v"(w1) : "v"(c0[2]), "v"(c0[3]));
      asm("v_cvt_pk_bf16_f32 %0, %1, %2" : "=v"(w2) : "v"(c1[0]), "v"(c1[1]));
      asm("v_cvt_pk_bf16_f32 %0, %1, %2" : "=v"(w3) : "v"(c1[2]), "v"(c1[3]));
      *(u32x2*)(Abf[p ^ 1] + co0) = (u32x2){w0, w1};
      *(u32x2*)(Abf[p ^ 1] + co1) = (u32x2){w2, w3};
      // (5) all LDS ops done; publish to the block
      asm volatile("s_waitcnt lgkmcnt(0)" ::: "memory");
      __builtin_amdgcn_s_barrier();
      __builtin_amdgcn_sched_barrier(0);
    }
    p ^= 1;
  }

  // Epilogue: C frag col=lane&15, row=(lane>>4)*4+reg; scatter rows via perm
  float bv[4];
  #pragma unroll
  for (int tn = 0; tn < 4; ++tn) bv[tn] = bias[ct * TN + wn + tn * 16 + fm];
  #pragma unroll
  for (int tm = 0; tm < 4; ++tm) {
    #pragma unroll
    for (int r = 0; r < 4; ++r) {
      const int mrow = wm + tm * 16 + (lane >> 4) * 4 + r;
      const int p2 = perm[rt * TM + mrow];
      if (p2 >= 0) {
        float* o = out + (size_t)p2 * D + ct * TN + wn + fm;
        #pragma unroll
        for (int tn = 0; tn < 4; ++tn)
          o[tn * 16] = acc[tm][tn][r] + bv[tn];
      }
    }
  }
}

extern "C" void kernel_launch(void* const* d_in, const int* in_sizes, int n_in,
                              void* d_out, int out_size, void* d_ws, size_t ws_size,
                              hipStream_t stream) {
  const float* x    = (const float*)d_in[0];
  const int*   val  = (const int*)d_in[1];
  const float* W    = (const float*)d_in[2];
  const float* lg   = (const float*)d_in[3];
  const float* attn = (const float*)d_in[4];
  const float* bias = (const float*)d_in[5];
  float* out = (float*)d_out;

  char* ws = (char*)d_ws;
  int* starts = (int*)(ws + 0);          // 11 ints
  u16* hist   = (u16*)(ws + 64);         // 128*10 u16
  int* perm   = (int*)(ws + 2688);       // 34048 ints -> ends 138880
  u16* weff   = (u16*)(ws + 139264);     // 10*512*512 bf16 = 5.24 MB

  k1<<<DD / 256 + NHB, 256, 0, stream>>>(W, lg, attn, val, weff, hist, perm);
  k2<<<NHB, 256, 0, stream>>>(val, hist, perm, starts);
  k3<<<dim3(D / TN, MAX_RT), 512, 0, stream>>>(x, weff, perm, starts, bias, out);
}